// Round 13
// baseline (2016.068 us; speedup 1.0000x reference)
//
#include <hip/hip_runtime.h>
#include <hip/hip_bf16.h>

// Shapes (fixed by the reference): B=32, T=2048, D=512, H=128.
#define Bx 32
#define Tt 2048
#define Dd 512
#define Hh 128
#define APS 152    // Ap row stride (shorts)
#define PROW 520   // padded panel row (floats)

typedef __attribute__((ext_vector_type(8))) short short8;   // 8 bf16 (4 VGPR)
typedef __attribute__((ext_vector_type(4))) float f32x4;    // MFMA C/D

static __device__ __forceinline__ short f2bf(float f) {
    __hip_bfloat16 h = __float2bfloat16(f);
    return *reinterpret_cast<short*>(&h);
}
static __device__ __forceinline__ float sigm(float x) {
    return 1.f / (1.f + __expf(-x));
}
static __device__ __forceinline__ float swz_xor16_add(float v) {
    return v + __int_as_float(__builtin_amdgcn_ds_swizzle(__float_as_int(v), 0x401F));
}

// barrier that does NOT drain vmcnt
#define BARRIER_LGKM() asm volatile("s_waitcnt lgkmcnt(0)\n\ts_barrier" ::: "memory")

// async global->LDS, 16B per lane
typedef __attribute__((address_space(1))) const void gas_void;
typedef __attribute__((address_space(3))) void las_void;
static __device__ __forceinline__ void gl_lds16(const float* g, float* l) {
    __builtin_amdgcn_global_load_lds((gas_void*)g, (las_void*)l, 16, 0, 0);
}

// ---------------------------------------------------------------------------
// Phase 1: G = x @ [W|...] + bias (bias folded into acc init). Verified R9-R12.
// ---------------------------------------------------------------------------
__global__ __launch_bounds__(512, 2) void gemm_xw_mfma(
    const float* __restrict__ X,
    const float* __restrict__ W0, const float* __restrict__ W1,
    const float* __restrict__ W2, const float* __restrict__ W3,
    const float* __restrict__ B0, const float* __restrict__ B1,
    const float* __restrict__ B2, const float* __restrict__ B3,
    float* __restrict__ G)
{
    __shared__ __align__(16) short As[128][40];
    __shared__ __align__(16) short Bs[512][40];

    const int tid  = threadIdx.x;
    const int m0   = blockIdx.x * 128;
    const int lane = tid & 63;
    const int w    = tid >> 6;
    const int wr   = w >> 2, wc = w & 3;
    const int l15  = lane & 15, kb = lane >> 4;

    const int bn   = tid;
    const int gate = bn >> 7;
    const int j    = bn & 127;
    const float* __restrict__ Wg = (gate == 0) ? W0 : (gate == 1) ? W1 : (gate == 2) ? W2 : W3;

    const int am = tid >> 2;
    const int ak = (tid & 3) * 8;

    const float* __restrict__ Bg = (wc == 0) ? B0 : (wc == 1) ? B1 : (wc == 2) ? B2 : B3;
    f32x4 acc[4][8];
    #pragma unroll
    for (int nt = 0; nt < 8; ++nt) {
        const float bv = Bg[nt * 16 + l15];
        #pragma unroll
        for (int mt = 0; mt < 4; ++mt)
            acc[mt][nt] = (f32x4){bv, bv, bv, bv};
    }

    for (int k0 = 0; k0 < Dd; k0 += 32) {
        {
            const float4* xp = (const float4*)&X[(size_t)(m0 + am) * Dd + k0 + ak];
            float4 v0 = xp[0], v1 = xp[1];
            short8 s;
            s[0] = f2bf(v0.x); s[1] = f2bf(v0.y); s[2] = f2bf(v0.z); s[3] = f2bf(v0.w);
            s[4] = f2bf(v1.x); s[5] = f2bf(v1.y); s[6] = f2bf(v1.z); s[7] = f2bf(v1.w);
            *(short8*)&As[am][ak] = s;
        }
        #pragma unroll
        for (int rc = 0; rc < 4; ++rc) {
            float v[8];
            #pragma unroll
            for (int r = 0; r < 8; ++r)
                v[r] = Wg[(size_t)(k0 + rc * 8 + r) * Hh + j];
            short8 s;
            #pragma unroll
            for (int r = 0; r < 8; ++r) s[r] = f2bf(v[r]);
            *(short8*)&Bs[bn][rc * 8] = s;
        }
        __syncthreads();

        short8 a[4], b[8];
        #pragma unroll
        for (int mt = 0; mt < 4; ++mt)
            a[mt] = *(const short8*)&As[wr * 64 + mt * 16 + l15][kb * 8];
        #pragma unroll
        for (int nt = 0; nt < 8; ++nt)
            b[nt] = *(const short8*)&Bs[wc * 128 + nt * 16 + l15][kb * 8];
        #pragma unroll
        for (int mt = 0; mt < 4; ++mt)
            #pragma unroll
            for (int nt = 0; nt < 8; ++nt)
                acc[mt][nt] = __builtin_amdgcn_mfma_f32_16x16x32_bf16(a[mt], b[nt], acc[mt][nt], 0, 0, 0);
        __syncthreads();
    }

    #pragma unroll
    for (int mt = 0; mt < 4; ++mt)
        #pragma unroll
        for (int nt = 0; nt < 8; ++nt)
            #pragma unroll
            for (int r = 0; r < 4; ++r)
                G[(size_t)(m0 + wr * 64 + mt * 16 + kb * 4 + r) * 512 + wc * 128 + nt * 16 + l15]
                    = acc[mt][nt][r];
}

// ---------------------------------------------------------------------------
// Phase 2: MFMA scan, TWO independent 2-batch chains per block.
// 8 blocks x 512 threads (8 waves): chain ch = w>>3?? no -> ch = w>>2,
// waves 0-3 = chain A (batches b0+0..1), waves 4-7 = chain B (b0+2..3).
// Each chain = R12's verified gate-per-wave machine: wave wc computes gate wc
// for its chain (operand-swapped MFMA: rows=j, cols=batch; layout verified
// R9/R10/R12), in-wave LN, 2 shared barriers/step. SIMD i hosts wave i and
// wave i+4 (independent chains) -> latency chains interleave.
// ---------------------------------------------------------------------------
__global__ __launch_bounds__(512, 2) void lstm_scan_mfma(
    const float* __restrict__ G,
    const float* __restrict__ Uf, const float* __restrict__ Ui,
    const float* __restrict__ Uo, const float* __restrict__ Uc,
    const float* __restrict__ lnfg, const float* __restrict__ lnfb,
    const float* __restrict__ lnig, const float* __restrict__ lnib,
    const float* __restrict__ lnog, const float* __restrict__ lnob,
    const float* __restrict__ lncg, const float* __restrict__ lncb,
    const float* __restrict__ h0, const float* __restrict__ c0,
    const int* __restrict__ zmask,
    float* __restrict__ out, float* __restrict__ hT)
{
    const int tid  = threadIdx.x;
    const int lane = tid & 63;
    const int w    = tid >> 6;          // wave 0..7
    const int ch   = w >> 2;            // chain 0/1
    const int wc   = w & 3;             // wave-in-chain = gate (phase A)
    const int b0   = blockIdx.x * 4;
    const int cb0  = b0 + ch * 2;       // chain's first batch
    const int l15  = lane & 15;
    const int kb   = lane >> 4;
    const int lb   = l15 & 1;           // clamped batch (2 per chain)

    __shared__ __align__(16) short Ap[2][16 * APS];          // [ch][b][k] bf16
    __shared__ __align__(16) float SLN[2][2][4][132];        // [ch][b][g][j]
    __shared__ __align__(16) float Pan[2 * 2 * 4 * 2 * PROW];// [buf][ch][slot][bb]
    __shared__ unsigned short act[Tt];
    __shared__ int wsum[8], wpre[8];
    __shared__ int nact_sh;

#define PIDX(buf, chq, slot, bb) (((((buf) * 2 + (chq)) * 4 + (slot)) * 2 + (bb)) * PROW)

    // ---- A fragments: gate wc, ALL 128 j (8 nt-tiles x 4 k-steps) ----
    const float* __restrict__ Ug = (wc == 0) ? Uf : (wc == 1) ? Ui : (wc == 2) ? Uo : Uc;
    short8 bfr[8][4];
    #pragma unroll
    for (int nt = 0; nt < 8; ++nt) {
        #pragma unroll
        for (int ks = 0; ks < 4; ++ks) {
            short8 v;
            #pragma unroll
            for (int r = 0; r < 8; ++r)
                v[r] = f2bf(Ug[(ks * 32 + kb * 8 + r) * Hh + nt * 16 + l15]);
            bfr[nt][ks] = v;
        }
    }

    // ---- owner (phase B) mapping: batch bq = wc>>1, col j = (wc&1)*64+lane ----
    const int bq = wc >> 1;
    const int oj = ((wc & 1) << 6) + lane;
    const float gF = lnfg[oj], bF = lnfb[oj];
    const float gI = lnig[oj], bI = lnib[oj];
    const float gO = lnog[oj], bO = lnob[oj];
    const float gC = lncg[oj], bC = lncb[oj];

    float hv = h0[(cb0 + bq) * Hh + oj];
    float cv = c0[(cb0 + bq) * Hh + oj];

    for (int i = tid; i < 2 * 16 * APS; i += 512) ((short*)Ap)[i] = 0;
    __syncthreads();
    Ap[ch][bq * APS + oj] = f2bf(hv);

    // ---- parallel active-list build (shared by both chains) ----
    {
        const int base_t = tid * 4;
        const int f0 = (zmask[base_t] == 0), f1 = (zmask[base_t + 1] == 0);
        const int f2 = (zmask[base_t + 2] == 0), f3 = (zmask[base_t + 3] == 0);
        const int cnt = f0 + f1 + f2 + f3;
        int scan = cnt;
        #pragma unroll
        for (int off = 1; off <= 32; off <<= 1) {
            int v = __shfl_up(scan, off);
            if (lane >= off) scan += v;
        }
        if (lane == 63) wsum[w] = scan;
        __syncthreads();
        if (tid == 0) {
            int s = 0;
            #pragma unroll
            for (int i = 0; i < 8; ++i) { wpre[i] = s; s += wsum[i]; }
            nact_sh = s;
        }
        __syncthreads();
        int pos = wpre[w] + scan - cnt;
        if (f0) act[pos++] = (unsigned short)(base_t);
        if (f1) act[pos++] = (unsigned short)(base_t + 1);
        if (f2) act[pos++] = (unsigned short)(base_t + 2);
        if (f3) act[pos++] = (unsigned short)(base_t + 3);
    }
    __syncthreads();
    const int nact = nact_sh;

    // leading zoneout steps: out = h0
    const int firstA = (nact > 0) ? (int)act[0] : Tt;
    for (int tt = 0; tt < firstA; ++tt)
        out[((size_t)(cb0 + bq) * Tt + tt) * Hh + oj] = hv;

    // ---- G panel staging: chain's wave wc loads slices {2wc, 2wc+1} ----
    auto stage_panel = [&](int kp, int buf) {
        #pragma unroll
        for (int si = 0; si < 2; ++si) {
            const int s    = wc * 2 + si;
            const int slot = s >> 1;
            const int bb   = s & 1;
            const int kidx = kp + slot;
            if (kidx < nact) {
                const int tt = (int)act[kidx];
                const float* src = &G[((size_t)(cb0 + bb) * Tt + tt) * 512];
                float* dst = &Pan[PIDX(buf, ch, slot, bb)];
                gl_lds16(src + lane * 4, dst);
                gl_lds16(src + 256 + lane * 4, dst + 256);
            }
        }
    };

    int cur = 0;
    stage_panel(0, 0);
    asm volatile("s_waitcnt vmcnt(0)" ::: "memory");
    __syncthreads();

    auto lstm_step = [&](int kidx, int slot) {
        const int t_ = (int)act[kidx];

        // ============ Phase A (wave = gate wc of chain ch) ============
        short8 a0 = *(const short8*)&Ap[ch][l15 * APS +  0 + kb * 8];
        short8 a1 = *(const short8*)&Ap[ch][l15 * APS + 32 + kb * 8];
        short8 a2 = *(const short8*)&Ap[ch][l15 * APS + 64 + kb * 8];
        short8 a3 = *(const short8*)&Ap[ch][l15 * APS + 96 + kb * 8];

        // C init = G+bias: batch lb, gate wc, j = nt*16 + kb*4 .. +3
        const int pbase = PIDX(cur, ch, slot, lb) + wc * 128 + kb * 4;
        f32x4 Cv[8];
        #pragma unroll
        for (int nt = 0; nt < 8; ++nt)
            Cv[nt] = *(const f32x4*)&Pan[pbase + nt * 16];

        #pragma unroll
        for (int nt = 0; nt < 8; ++nt)
            Cv[nt] = __builtin_amdgcn_mfma_f32_16x16x32_bf16(bfr[nt][0], a0, Cv[nt], 0, 0, 0);
        #pragma unroll
        for (int nt = 0; nt < 8; ++nt)
            Cv[nt] = __builtin_amdgcn_mfma_f32_16x16x32_bf16(bfr[nt][1], a1, Cv[nt], 0, 0, 0);
        #pragma unroll
        for (int nt = 0; nt < 8; ++nt)
            Cv[nt] = __builtin_amdgcn_mfma_f32_16x16x32_bf16(bfr[nt][2], a2, Cv[nt], 0, 0, 0);
        #pragma unroll
        for (int nt = 0; nt < 8; ++nt)
            Cv[nt] = __builtin_amdgcn_mfma_f32_16x16x32_bf16(bfr[nt][3], a3, Cv[nt], 0, 0, 0);

        // in-wave LN stats: lane holds 32 j-values of (batch l15, gate wc)
        float sm = 0.f, sq = 0.f;
        #pragma unroll
        for (int nt = 0; nt < 8; ++nt)
            #pragma unroll
            for (int r = 0; r < 4; ++r) {
                sm += Cv[nt][r];
                sq = fmaf(Cv[nt][r], Cv[nt][r], sq);
            }
        sm = swz_xor16_add(sm);          // fold kb 0<->1, 2<->3 (l15 preserved)
        sq = swz_xor16_add(sq);
        sm += __shfl_xor(sm, 32);        // fold kb {0,1} <-> {2,3}
        sq += __shfl_xor(sq, 32);
        const float mu   = sm * (1.f / 128.f);
        const float rstd = rsqrtf(sq * (1.f / 128.f) - mu * mu + 1e-5f);
        const float na = rstd, nc = -mu * rstd;
        #pragma unroll
        for (int nt = 0; nt < 8; ++nt)
            #pragma unroll
            for (int r = 0; r < 4; ++r)
                Cv[nt][r] = fmaf(Cv[nt][r], na, nc);

        if (l15 < 2) {
            #pragma unroll
            for (int nt = 0; nt < 8; ++nt)
                *(f32x4*)&SLN[ch][l15][wc][nt * 16 + kb * 4] = Cv[nt];
        }
        BARRIER_LGKM();

        // ============ Phase B (thread = chain ch, batch bq, col oj) ============
        {
            const float nf  = SLN[ch][bq][0][oj];
            const float ni  = SLN[ch][bq][1][oj];
            const float no_ = SLN[ch][bq][2][oj];
            const float ng  = SLN[ch][bq][3][oj];
            const float f_ = sigm(fmaf(nf,  gF, bF));
            const float i_ = sigm(fmaf(ni,  gI, bI));
            const float o_ = sigm(fmaf(no_, gO, bO));
            const float g_ = sigm(fmaf(ng,  gC, bC));
            cv = f_ * cv + i_ * g_;
            hv = o_ * sigm(cv);                      // NB: sigmoid, not tanh
            Ap[ch][bq * APS + oj] = f2bf(hv);
            out[((size_t)(cb0 + bq) * Tt + t_) * Hh + oj] = hv;
        }
        BARRIER_LGKM();
    };

    for (int kp = 0; kp < nact; kp += 4) {
        stage_panel(kp + 4, cur ^ 1);                // issue next panel early
        const int lim = (nact - kp < 4) ? (nact - kp) : 4;
        #pragma unroll
        for (int sl = 0; sl < 4; ++sl) {
            if (sl < lim) {
                lstm_step(kp + sl, sl);
                if (sl == 3)                          // once per group: drain DMA
                    asm volatile("s_waitcnt vmcnt(0)" ::: "memory");
            }
        }
        cur ^= 1;
    }

    hT[(cb0 + bq) * Hh + oj] = hv;
#undef PIDX
}

// ---------------------------------------------------------------------------
// Phase 3: fill zoneout timesteps (verified R7-R12).
// ---------------------------------------------------------------------------
__global__ __launch_bounds__(512) void fill_zoneout(
    const int* __restrict__ zmask, const float* __restrict__ h0,
    float* __restrict__ out)
{
    const int t = blockIdx.x;
    if (zmask[t] == 0) return;            // active: scan wrote it
    int s = t - 1;
    while (s >= 0 && zmask[s] != 0) --s;
    const int tid = threadIdx.x;
    for (int idx = tid; idx < Bx * Hh; idx += 512) {
        const int b = idx >> 7, j = idx & 127;
        const float v = (s >= 0) ? out[((size_t)b * Tt + s) * Hh + j]
                                 : h0[b * Hh + j];
        out[((size_t)b * Tt + t) * Hh + j] = v;
    }
}

// ---------------------------------------------------------------------------
extern "C" void kernel_launch(void* const* d_in, const int* in_sizes, int n_in,
                              void* d_out, int out_size, void* d_ws, size_t ws_size,
                              hipStream_t stream)
{
    const float* x   = (const float*)d_in[0];
    const float* W_f = (const float*)d_in[1];
    const float* W_i = (const float*)d_in[2];
    const float* W_o = (const float*)d_in[3];
    const float* W_c = (const float*)d_in[4];
    const float* U_f = (const float*)d_in[5];
    const float* U_i = (const float*)d_in[6];
    const float* U_o = (const float*)d_in[7];
    const float* U_c = (const float*)d_in[8];
    const float* b_f = (const float*)d_in[9];
    const float* b_i = (const float*)d_in[10];
    const float* b_o = (const float*)d_in[11];
    const float* b_c = (const float*)d_in[12];
    const float* ln_f_g = (const float*)d_in[13];
    const float* ln_f_b = (const float*)d_in[14];
    const float* ln_i_g = (const float*)d_in[15];
    const float* ln_i_b = (const float*)d_in[16];
    const float* ln_o_g = (const float*)d_in[17];
    const float* ln_o_b = (const float*)d_in[18];
    const float* ln_c_g = (const float*)d_in[19];
    const float* ln_c_b = (const float*)d_in[20];
    const float* h0  = (const float*)d_in[21];
    const float* c0  = (const float*)d_in[22];
    const int*   zm  = (const int*)d_in[23];

    float* out = (float*)d_out;                       // [B, T, H]
    float* hT  = out + (size_t)Bx * Tt * Hh;          // [B, H]
    float* G   = (float*)d_ws;                        // [B*T, 512] = 128 MiB

    gemm_xw_mfma<<<(Bx * Tt) / 128, 512, 0, stream>>>(x, W_f, W_i, W_o, W_c,
                                                      b_f, b_i, b_o, b_c, G);

    lstm_scan_mfma<<<8, 512, 0, stream>>>(G, U_f, U_i, U_o, U_c,
                                          ln_f_g, ln_f_b, ln_i_g, ln_i_b,
                                          ln_o_g, ln_o_b, ln_c_g, ln_c_b,
                                          h0, c0, zm, out, hT);

    fill_zoneout<<<Tt, 512, 0, stream>>>(zm, h0, out);
}

// Round 14
// 1427.315 us; speedup vs baseline: 1.4125x; 1.4125x over previous
//
#include <hip/hip_runtime.h>
#include <hip/hip_bf16.h>

// Shapes (fixed by the reference): B=32, T=2048, D=512, H=128.
#define Bx 32
#define Tt 2048
#define Dd 512
#define Hh 128
#define APS 152    // Ap row stride (shorts)
#define PROW 520   // padded panel row (floats)
#define SGS 528    // SLN gate stride (floats) = 4*132

typedef __attribute__((ext_vector_type(8))) short short8;   // 8 bf16 (4 VGPR)
typedef __attribute__((ext_vector_type(4))) float f32x4;    // MFMA C/D

static __device__ __forceinline__ short f2bf(float f) {
    __hip_bfloat16 h = __float2bfloat16(f);
    return *reinterpret_cast<short*>(&h);
}
// fast sigmoid: v_rcp_f32 (~1 ulp) instead of IEEE divide (~11 instrs).
// absmax headroom 4x; error passes through saturating gates.
static __device__ __forceinline__ float sigm(float x) {
    return __builtin_amdgcn_rcpf(1.f + __expf(-x));
}
static __device__ __forceinline__ float swz_xor16_add(float v) {
    return v + __int_as_float(__builtin_amdgcn_ds_swizzle(__float_as_int(v), 0x401F));
}

// barrier that does NOT drain vmcnt
#define BARRIER_LGKM() asm volatile("s_waitcnt lgkmcnt(0)\n\ts_barrier" ::: "memory")

// async global->LDS, 16B per lane
typedef __attribute__((address_space(1))) const void gas_void;
typedef __attribute__((address_space(3))) void las_void;
static __device__ __forceinline__ void gl_lds16(const float* g, float* l) {
    __builtin_amdgcn_global_load_lds((gas_void*)g, (las_void*)l, 16, 0, 0);
}

// ---------------------------------------------------------------------------
// Phase 1: G = x @ [W|...] + bias (bias folded into acc init). Verified R9-R13.
// ---------------------------------------------------------------------------
__global__ __launch_bounds__(512, 2) void gemm_xw_mfma(
    const float* __restrict__ X,
    const float* __restrict__ W0, const float* __restrict__ W1,
    const float* __restrict__ W2, const float* __restrict__ W3,
    const float* __restrict__ B0, const float* __restrict__ B1,
    const float* __restrict__ B2, const float* __restrict__ B3,
    float* __restrict__ G)
{
    __shared__ __align__(16) short As[128][40];
    __shared__ __align__(16) short Bs[512][40];

    const int tid  = threadIdx.x;
    const int m0   = blockIdx.x * 128;
    const int lane = tid & 63;
    const int w    = tid >> 6;
    const int wr   = w >> 2, wc = w & 3;
    const int l15  = lane & 15, kb = lane >> 4;

    const int bn   = tid;
    const int gate = bn >> 7;
    const int j    = bn & 127;
    const float* __restrict__ Wg = (gate == 0) ? W0 : (gate == 1) ? W1 : (gate == 2) ? W2 : W3;

    const int am = tid >> 2;
    const int ak = (tid & 3) * 8;

    const float* __restrict__ Bg = (wc == 0) ? B0 : (wc == 1) ? B1 : (wc == 2) ? B2 : B3;
    f32x4 acc[4][8];
    #pragma unroll
    for (int nt = 0; nt < 8; ++nt) {
        const float bv = Bg[nt * 16 + l15];
        #pragma unroll
        for (int mt = 0; mt < 4; ++mt)
            acc[mt][nt] = (f32x4){bv, bv, bv, bv};
    }

    for (int k0 = 0; k0 < Dd; k0 += 32) {
        {
            const float4* xp = (const float4*)&X[(size_t)(m0 + am) * Dd + k0 + ak];
            float4 v0 = xp[0], v1 = xp[1];
            short8 s;
            s[0] = f2bf(v0.x); s[1] = f2bf(v0.y); s[2] = f2bf(v0.z); s[3] = f2bf(v0.w);
            s[4] = f2bf(v1.x); s[5] = f2bf(v1.y); s[6] = f2bf(v1.z); s[7] = f2bf(v1.w);
            *(short8*)&As[am][ak] = s;
        }
        #pragma unroll
        for (int rc = 0; rc < 4; ++rc) {
            float v[8];
            #pragma unroll
            for (int r = 0; r < 8; ++r)
                v[r] = Wg[(size_t)(k0 + rc * 8 + r) * Hh + j];
            short8 s;
            #pragma unroll
            for (int r = 0; r < 8; ++r) s[r] = f2bf(v[r]);
            *(short8*)&Bs[bn][rc * 8] = s;
        }
        __syncthreads();

        short8 a[4], b[8];
        #pragma unroll
        for (int mt = 0; mt < 4; ++mt)
            a[mt] = *(const short8*)&As[wr * 64 + mt * 16 + l15][kb * 8];
        #pragma unroll
        for (int nt = 0; nt < 8; ++nt)
            b[nt] = *(const short8*)&Bs[wc * 128 + nt * 16 + l15][kb * 8];
        #pragma unroll
        for (int mt = 0; mt < 4; ++mt)
            #pragma unroll
            for (int nt = 0; nt < 8; ++nt)
                acc[mt][nt] = __builtin_amdgcn_mfma_f32_16x16x32_bf16(a[mt], b[nt], acc[mt][nt], 0, 0, 0);
        __syncthreads();
    }

    #pragma unroll
    for (int mt = 0; mt < 4; ++mt)
        #pragma unroll
        for (int nt = 0; nt < 8; ++nt)
            #pragma unroll
            for (int r = 0; r < 4; ++r)
                G[(size_t)(m0 + wr * 64 + mt * 16 + kb * 4 + r) * 512 + wc * 128 + nt * 16 + l15]
                    = acc[mt][nt][r];
}

// ---------------------------------------------------------------------------
// Phase 2: MFMA scan — exact R12 structure (best measured: 1513us) with
// fast-math micro-ops: v_rcp sigmoid, v_rsq LN, 32-bit out addressing.
// ---------------------------------------------------------------------------
__global__ __launch_bounds__(256, 1) void lstm_scan_mfma(
    const float* __restrict__ G,
    const float* __restrict__ Uf, const float* __restrict__ Ui,
    const float* __restrict__ Uo, const float* __restrict__ Uc,
    const float* __restrict__ lnfg, const float* __restrict__ lnfb,
    const float* __restrict__ lnig, const float* __restrict__ lnib,
    const float* __restrict__ lnog, const float* __restrict__ lnob,
    const float* __restrict__ lncg, const float* __restrict__ lncb,
    const float* __restrict__ h0, const float* __restrict__ c0,
    const int* __restrict__ zmask,
    float* __restrict__ out, float* __restrict__ hT)
{
    const int tid  = threadIdx.x;
    const int lane = tid & 63;
    const int w    = tid >> 6;          // wave 0..3 = gate (phase A) / batch (phase B)
    const int b0   = blockIdx.x * 4;    // 4 batches per block
    const int l15  = lane & 15;
    const int kb   = lane >> 4;

    __shared__ __align__(16) short Ap[16 * APS];           // h panel bf16 [b][k]
    __shared__ __align__(16) float SLN[4 * SGS];           // [g][b][j] normalized
    __shared__ __align__(16) float Pan[2 * 4 * 4 * PROW];  // [buf][slot][b][col]
    __shared__ unsigned short act[Tt];
    __shared__ int wsum[4], wpre[4];
    __shared__ int nact_sh;

    // ---- A fragments: wave's gate, ALL 128 j (8 nt-tiles x 4 k-steps) ----
    const float* __restrict__ Ug = (w == 0) ? Uf : (w == 1) ? Ui : (w == 2) ? Uo : Uc;
    short8 bfr[8][4];
    #pragma unroll
    for (int nt = 0; nt < 8; ++nt) {
        #pragma unroll
        for (int ks = 0; ks < 4; ++ks) {
            short8 v;
            #pragma unroll
            for (int r = 0; r < 8; ++r)
                v[r] = f2bf(Ug[(ks * 32 + kb * 8 + r) * Hh + nt * 16 + l15]);
            bfr[nt][ks] = v;
        }
    }

    // ---- owner constants: thread = (batch w, cols j1 = lane, j2 = lane+64) ----
    const int j1 = lane, j2 = lane + 64;
    const float gF1 = lnfg[j1], bF1 = lnfb[j1], gF2 = lnfg[j2], bF2 = lnfb[j2];
    const float gI1 = lnig[j1], bI1 = lnib[j1], gI2 = lnig[j2], bI2 = lnib[j2];
    const float gO1 = lnog[j1], bO1 = lnob[j1], gO2 = lnog[j2], bO2 = lnob[j2];
    const float gC1 = lncg[j1], bC1 = lncb[j1], gC2 = lncg[j2], bC2 = lncb[j2];

    float hv0 = h0[(b0 + w) * Hh + j1];
    float hv1 = h0[(b0 + w) * Hh + j2];
    float cv0 = c0[(b0 + w) * Hh + j1];
    float cv1 = c0[(b0 + w) * Hh + j2];

    // 32-bit-offset out base for this thread's batch row (kills 64-bit mul/step)
    float* __restrict__ outb = out + (size_t)(b0 + w) * Tt * Hh;

    for (int i = tid; i < 16 * APS; i += 256) Ap[i] = 0;
    __syncthreads();
    Ap[w * APS + j1] = f2bf(hv0);
    Ap[w * APS + j2] = f2bf(hv1);

    // ---- parallel active-list build (8 flags per thread) ----
    {
        const int base_t = tid * 8;
        int fl[8], cnt = 0;
        #pragma unroll
        for (int i = 0; i < 8; ++i) { fl[i] = (zmask[base_t + i] == 0); cnt += fl[i]; }
        int scan = cnt;
        #pragma unroll
        for (int off = 1; off <= 32; off <<= 1) {
            int v = __shfl_up(scan, off);
            if (lane >= off) scan += v;
        }
        if (lane == 63) wsum[w] = scan;
        __syncthreads();
        if (tid == 0) {
            int s = 0;
            #pragma unroll
            for (int i = 0; i < 4; ++i) { wpre[i] = s; s += wsum[i]; }
            nact_sh = s;
        }
        __syncthreads();
        int pos = wpre[w] + scan - cnt;
        #pragma unroll
        for (int i = 0; i < 8; ++i)
            if (fl[i]) act[pos++] = (unsigned short)(base_t + i);
    }
    __syncthreads();
    const int nact = nact_sh;

    // leading zoneout steps: out = h0
    const int firstA = (nact > 0) ? (int)act[0] : Tt;
    for (int tt = 0; tt < firstA; ++tt) {
        outb[(tt << 7) + j1] = hv0;
        outb[(tt << 7) + j2] = hv1;
    }

    // ---- G panel staging: wave w loads 4 slices (slot s>>2, batch s&3) ----
    auto stage_panel = [&](int kp, int buf) {
        #pragma unroll
        for (int si = 0; si < 4; ++si) {
            const int s    = w * 4 + si;
            const int slot = s >> 2;
            const int bb   = s & 3;
            const int kidx = kp + slot;
            if (kidx < nact) {
                const int tt = (int)act[kidx];
                const float* src = &G[((size_t)(b0 + bb) * Tt + tt) * 512];
                float* dst = &Pan[((buf * 4 + slot) * 4 + bb) * PROW];
                gl_lds16(src + lane * 4, dst);
                gl_lds16(src + 256 + lane * 4, dst + 256);
            }
        }
    };

    int cur = 0;
    stage_panel(0, 0);
    asm volatile("s_waitcnt vmcnt(0)" ::: "memory");
    __syncthreads();

    const int lb = l15 & 3;   // clamped batch for panel reads

    auto lstm_step = [&](int kidx, int slot) {
        const int t_ = (int)act[kidx];

        // ============ Phase A (wave = gate) ============
        short8 a0 = *(const short8*)&Ap[l15 * APS +  0 + kb * 8];
        short8 a1 = *(const short8*)&Ap[l15 * APS + 32 + kb * 8];
        short8 a2 = *(const short8*)&Ap[l15 * APS + 64 + kb * 8];
        short8 a3 = *(const short8*)&Ap[l15 * APS + 96 + kb * 8];

        // C init = G+bias: batch lb, gate w, j = nt*16 + kb*4 .. +3
        const int pbase = ((cur * 4 + slot) * 4 + lb) * PROW + w * 128 + kb * 4;
        f32x4 Cv[8];
        #pragma unroll
        for (int nt = 0; nt < 8; ++nt)
            Cv[nt] = *(const f32x4*)&Pan[pbase + nt * 16];

        #pragma unroll
        for (int nt = 0; nt < 8; ++nt)
            Cv[nt] = __builtin_amdgcn_mfma_f32_16x16x32_bf16(bfr[nt][0], a0, Cv[nt], 0, 0, 0);
        #pragma unroll
        for (int nt = 0; nt < 8; ++nt)
            Cv[nt] = __builtin_amdgcn_mfma_f32_16x16x32_bf16(bfr[nt][1], a1, Cv[nt], 0, 0, 0);
        #pragma unroll
        for (int nt = 0; nt < 8; ++nt)
            Cv[nt] = __builtin_amdgcn_mfma_f32_16x16x32_bf16(bfr[nt][2], a2, Cv[nt], 0, 0, 0);
        #pragma unroll
        for (int nt = 0; nt < 8; ++nt)
            Cv[nt] = __builtin_amdgcn_mfma_f32_16x16x32_bf16(bfr[nt][3], a3, Cv[nt], 0, 0, 0);

        // in-wave LN stats: lane holds 32 j-values of (batch l15, gate w)
        float sm = 0.f, sq = 0.f;
        #pragma unroll
        for (int nt = 0; nt < 8; ++nt)
            #pragma unroll
            for (int r = 0; r < 4; ++r) {
                sm += Cv[nt][r];
                sq = fmaf(Cv[nt][r], Cv[nt][r], sq);
            }
        sm = swz_xor16_add(sm);          // fold kb 0<->1, 2<->3
        sq = swz_xor16_add(sq);
        sm += __shfl_xor(sm, 32);        // fold kb {0,1} <-> {2,3}
        sq += __shfl_xor(sq, 32);
        const float mu   = sm * (1.f / 128.f);
        const float rstd = __builtin_amdgcn_rsqf(
            fmaf(sq, 1.f / 128.f, -mu * mu) + 1e-5f);
        const float na = rstd, nc = -mu * rstd;
        #pragma unroll
        for (int nt = 0; nt < 8; ++nt)
            #pragma unroll
            for (int r = 0; r < 4; ++r)
                Cv[nt][r] = fmaf(Cv[nt][r], na, nc);

        if (l15 < 4) {
            #pragma unroll
            for (int nt = 0; nt < 8; ++nt)
                *(f32x4*)&SLN[w * SGS + l15 * 132 + nt * 16 + kb * 4] = Cv[nt];
        }
        BARRIER_LGKM();

        // ============ Phase B (wave = batch w, lane = j) ============
        {
            const int sb = w * 132;
            const float nf0 = SLN[0 * SGS + sb + j1], nf1 = SLN[0 * SGS + sb + j2];
            const float ni0 = SLN[1 * SGS + sb + j1], ni1 = SLN[1 * SGS + sb + j2];
            const float no0 = SLN[2 * SGS + sb + j1], no1 = SLN[2 * SGS + sb + j2];
            const float nc0 = SLN[3 * SGS + sb + j1], nc1 = SLN[3 * SGS + sb + j2];
            const float f0 = sigm(fmaf(nf0, gF1, bF1));
            const float i0 = sigm(fmaf(ni0, gI1, bI1));
            const float o0 = sigm(fmaf(no0, gO1, bO1));
            const float g0 = sigm(fmaf(nc0, gC1, bC1));
            const float f1 = sigm(fmaf(nf1, gF2, bF2));
            const float i1 = sigm(fmaf(ni1, gI2, bI2));
            const float o1 = sigm(fmaf(no1, gO2, bO2));
            const float g1 = sigm(fmaf(nc1, gC2, bC2));
            cv0 = f0 * cv0 + i0 * g0;
            hv0 = o0 * sigm(cv0);                    // NB: sigmoid, not tanh
            cv1 = f1 * cv1 + i1 * g1;
            hv1 = o1 * sigm(cv1);
            Ap[w * APS + j1] = f2bf(hv0);
            Ap[w * APS + j2] = f2bf(hv1);
            outb[(t_ << 7) + j1] = hv0;
            outb[(t_ << 7) + j2] = hv1;
        }
        BARRIER_LGKM();
    };

    for (int kp = 0; kp < nact; kp += 4) {
        stage_panel(kp + 4, cur ^ 1);                // issue next panel early
        const int lim = (nact - kp < 4) ? (nact - kp) : 4;
        #pragma unroll
        for (int sl = 0; sl < 4; ++sl) {
            if (sl < lim) {
                lstm_step(kp + sl, sl);
                if (sl == 3)                          // once per group: drain DMA
                    asm volatile("s_waitcnt vmcnt(0)" ::: "memory");
            }
        }
        cur ^= 1;
    }

    hT[(b0 + w) * Hh + j1] = hv0;
    hT[(b0 + w) * Hh + j2] = hv1;
}

// ---------------------------------------------------------------------------
// Phase 3: fill zoneout timesteps (verified R7-R13).
// ---------------------------------------------------------------------------
__global__ __launch_bounds__(512) void fill_zoneout(
    const int* __restrict__ zmask, const float* __restrict__ h0,
    float* __restrict__ out)
{
    const int t = blockIdx.x;
    if (zmask[t] == 0) return;            // active: scan wrote it
    int s = t - 1;
    while (s >= 0 && zmask[s] != 0) --s;
    const int tid = threadIdx.x;
    for (int idx = tid; idx < Bx * Hh; idx += 512) {
        const int b = idx >> 7, j = idx & 127;
        const float v = (s >= 0) ? out[((size_t)b * Tt + s) * Hh + j]
                                 : h0[b * Hh + j];
        out[((size_t)b * Tt + t) * Hh + j] = v;
    }
}

// ---------------------------------------------------------------------------
extern "C" void kernel_launch(void* const* d_in, const int* in_sizes, int n_in,
                              void* d_out, int out_size, void* d_ws, size_t ws_size,
                              hipStream_t stream)
{
    const float* x   = (const float*)d_in[0];
    const float* W_f = (const float*)d_in[1];
    const float* W_i = (const float*)d_in[2];
    const float* W_o = (const float*)d_in[3];
    const float* W_c = (const float*)d_in[4];
    const float* U_f = (const float*)d_in[5];
    const float* U_i = (const float*)d_in[6];
    const float* U_o = (const float*)d_in[7];
    const float* U_c = (const float*)d_in[8];
    const float* b_f = (const float*)d_in[9];
    const float* b_i = (const float*)d_in[10];
    const float* b_o = (const float*)d_in[11];
    const float* b_c = (const float*)d_in[12];
    const float* ln_f_g = (const float*)d_in[13];
    const float* ln_f_b = (const float*)d_in[14];
    const float* ln_i_g = (const float*)d_in[15];
    const float* ln_i_b = (const float*)d_in[16];
    const float* ln_o_g = (const float*)d_in[17];
    const float* ln_o_b = (const float*)d_in[18];
    const float* ln_c_g = (const float*)d_in[19];
    const float* ln_c_b = (const float*)d_in[20];
    const float* h0  = (const float*)d_in[21];
    const float* c0  = (const float*)d_in[22];
    const int*   zm  = (const int*)d_in[23];

    float* out = (float*)d_out;                       // [B, T, H]
    float* hT  = out + (size_t)Bx * Tt * Hh;          // [B, H]
    float* G   = (float*)d_ws;                        // [B*T, 512] = 128 MiB

    gemm_xw_mfma<<<(Bx * Tt) / 128, 512, 0, stream>>>(x, W_f, W_i, W_o, W_c,
                                                      b_f, b_i, b_o, b_c, G);

    lstm_scan_mfma<<<8, 256, 0, stream>>>(G, U_f, U_i, U_o, U_c,
                                          ln_f_g, ln_f_b, ln_i_g, ln_i_b,
                                          ln_o_g, ln_o_b, ln_c_g, ln_c_b,
                                          h0, c0, zm, out, hT);

    fill_zoneout<<<Tt, 512, 0, stream>>>(zm, h0, out);
}